// Round 1
// baseline (318.120 us; speedup 1.0000x reference)
//
#include <hip/hip_runtime.h>
#include <math.h>

#define EPS_C      1e-05f
#define PROJ_EPS_C 0.004f
#define MIN_NORM_C 1e-15f

#define NTOK   4096
#define DH     64
#define TILE   64
#define CHUNK  512
#define NCHUNK (NTOK / CHUNK)
#define PADROW 68   // 64 + 4 pad: keeps float4 alignment, spreads LDS banks

__device__ __forceinline__ float elup(float z) {
    // elu(z) + 1
    return z > 0.f ? z + 1.f : __expf(z);
}

// ---------------------------------------------------------------------------
// Phase 1: from K, V compute per-token pt, and accumulate v2_sum[64] and
// context[64][64] = sum_n v2[n][d] * x_scaled[n][e]  (atomicAdd into ws)
// ---------------------------------------------------------------------------
__global__ __launch_bounds__(256) void glin_phase1(
    const float* __restrict__ Kk, const float* __restrict__ Vv,
    const float* __restrict__ mask, const float* __restrict__ cc,
    int csize, int H,
    float* __restrict__ pt_out, float* __restrict__ v2sum_out,
    float* __restrict__ ctx_out)
{
    __shared__ __align__(16) float v2s[TILE][PADROW];
    __shared__ __align__(16) float xss[TILE][PADROW];

    const int bh    = blockIdx.x;
    const int chunk = blockIdx.y;
    const int h     = bh % H;
    const float k   = cc[(csize == 1) ? 0 : h];

    const float* Kp = Kk + (size_t)bh * NTOK * DH;
    const float* Vp = Vv + (size_t)bh * NTOK * DH;
    float* ptp      = pt_out + (size_t)bh * NTOK;

    const int tid = threadIdx.x;
    const int ty  = tid >> 4;   // 0..15 -> d block
    const int tx  = tid & 15;   // 0..15 -> e block

    float acc[4][4];
#pragma unroll
    for (int i = 0; i < 4; ++i)
#pragma unroll
        for (int j = 0; j < 4; ++j) acc[i][j] = 0.f;
    float v2acc[4] = {0.f, 0.f, 0.f, 0.f};

    const int tbase = chunk * CHUNK;
    for (int tt = 0; tt < CHUNK; tt += TILE) {
        // ---- stage + transform one 64-token tile ----
#pragma unroll
        for (int p = 0; p < 4; ++p) {
            int f   = tid + p * 256;
            int row = f >> 4;       // local token 0..63
            int c4  = f & 15;       // float4 column 0..15
            int gtok = tbase + tt + row;
            float4 v4 = *(const float4*)(Vp + (size_t)gtok * DH + c4 * 4);
            float4 k4 = *(const float4*)(Kp + (size_t)gtok * DH + c4 * 4);
            // ||V_row||^2 via 16-lane reduction (lanes of same row are consecutive)
            float ss = v4.x * v4.x + v4.y * v4.y + v4.z * v4.z + v4.w * v4.w;
            ss += __shfl_xor(ss, 1);
            ss += __shfl_xor(ss, 2);
            ss += __shfl_xor(ss, 4);
            ss += __shfl_xor(ss, 8);
            float dpt   = fmaxf(1.f + k * ss, MIN_NORM_C);
            float pt    = 1.f / dpt;
            float gamma = 2.f * pt;
            float gm1   = gamma - 1.f;
            float sg    = (gm1 < 0.f) ? -1.f : 1.f;   // _sign(0) = +1
            float denomG = sg * fmaxf(fabsf(gm1), 1e-10f);
            float m     = mask[gtok];
            float xsc   = gamma / denomG * m;
            float a2    = denomG * m;
            if (c4 == 0) ptp[gtok] = pt;
            float4 xs4;
            xs4.x = v4.x * xsc; xs4.y = v4.y * xsc;
            xs4.z = v4.z * xsc; xs4.w = v4.w * xsc;
            float4 w4;
            w4.x = a2 * elup(k4.x * pt);
            w4.y = a2 * elup(k4.y * pt);
            w4.z = a2 * elup(k4.z * pt);
            w4.w = a2 * elup(k4.w * pt);
            *(float4*)&xss[row][c4 * 4] = xs4;
            *(float4*)&v2s[row][c4 * 4] = w4;
        }
        __syncthreads();
        // ---- outer-product accumulate: acc[d][e] += v2[t][d] * xs[t][e] ----
#pragma unroll 4
        for (int t = 0; t < TILE; ++t) {
            float4 a = *(const float4*)&v2s[t][ty * 4];
            float4 b = *(const float4*)&xss[t][tx * 4];
            float av[4] = {a.x, a.y, a.z, a.w};
            float bv[4] = {b.x, b.y, b.z, b.w};
#pragma unroll
            for (int i = 0; i < 4; ++i) {
                v2acc[i] += av[i];
#pragma unroll
                for (int j = 0; j < 4; ++j)
                    acc[i][j] = fmaf(av[i], bv[j], acc[i][j]);
            }
        }
        __syncthreads();
    }

    float* ctx = ctx_out + (size_t)bh * DH * DH;
#pragma unroll
    for (int i = 0; i < 4; ++i)
#pragma unroll
        for (int j = 0; j < 4; ++j)
            atomicAdd(&ctx[(ty * 4 + i) * DH + tx * 4 + j], acc[i][j]);
    if (tx == 0) {
#pragma unroll
        for (int i = 0; i < 4; ++i)
            atomicAdd(&v2sum_out[(size_t)bh * DH + ty * 4 + i], v2acc[i]);
    }
}

// ---------------------------------------------------------------------------
// Phase 2: from Q, pt, v2_sum, context compute
//   v1 = elup(Q*pt); D = v1.v2_sum; X = (v1 @ context)/D; project->mobius(0.5)->project
// ---------------------------------------------------------------------------
__global__ __launch_bounds__(256) void glin_phase2(
    const float* __restrict__ Qq, const float* __restrict__ cc,
    int csize, int H,
    const float* __restrict__ pt_in, const float* __restrict__ v2sum_in,
    const float* __restrict__ ctx_in, float* __restrict__ out)
{
    __shared__ __align__(16) float ctxs[DH][PADROW];
    __shared__ __align__(16) float v1t[DH][PADROW];   // v1 transposed: [d][token]
    __shared__ __align__(16) float v2sum[DH];
    __shared__ float dinv[TILE];
    __shared__ __align__(16) float ptl[CHUNK];

    const int bh    = blockIdx.x;
    const int chunk = blockIdx.y;
    const int h     = bh % H;
    const float k   = cc[(csize == 1) ? 0 : h];
    const float sk  = sqrtf(fabsf(k) + MIN_NORM_C);
    const float maxnorm = (k < 0.f) ? (1.f - PROJ_EPS_C) / sk : 1e15f;

    const int tid = threadIdx.x;
    const int ty  = tid >> 4;
    const int tx  = tid & 15;

    const float* Qp = Qq + (size_t)bh * NTOK * DH;
    float* outp     = out + (size_t)bh * NTOK * DH;

    // load context into LDS (padded)
#pragma unroll
    for (int p = 0; p < 4; ++p) {
        int f = tid + p * 256;
        int d = f >> 4, c4 = f & 15;
        float4 v = *(const float4*)(ctx_in + (size_t)bh * DH * DH + d * DH + c4 * 4);
        *(float4*)&ctxs[d][c4 * 4] = v;
    }
    if (tid < 16) {
        float4 v = *(const float4*)(v2sum_in + (size_t)bh * DH + tid * 4);
        *(float4*)&v2sum[tid * 4] = v;
    }
    if (tid < CHUNK / 4) {
        float4 v = *(const float4*)(pt_in + (size_t)bh * NTOK + chunk * CHUNK + tid * 4);
        *(float4*)&ptl[tid * 4] = v;
    }
    __syncthreads();

    const int tbase = chunk * CHUNK;
    for (int tt = 0; tt < CHUNK; tt += TILE) {
        // ---- build v1^T tile + Dinv ----
#pragma unroll
        for (int p = 0; p < 4; ++p) {
            int f   = tid + p * 256;
            int row = f >> 4;        // local token 0..63
            int c4  = f & 15;
            int gtok = tbase + tt + row;
            float4 q4 = *(const float4*)(Qp + (size_t)gtok * DH + c4 * 4);
            float ptv = ptl[tt + row];
            float4 v1;
            v1.x = elup(q4.x * ptv);
            v1.y = elup(q4.y * ptv);
            v1.z = elup(q4.z * ptv);
            v1.w = elup(q4.w * ptv);
            float4 vs = *(const float4*)&v2sum[c4 * 4];
            float dp = v1.x * vs.x + v1.y * vs.y + v1.z * vs.z + v1.w * vs.w;
            dp += __shfl_xor(dp, 1);
            dp += __shfl_xor(dp, 2);
            dp += __shfl_xor(dp, 4);
            dp += __shfl_xor(dp, 8);
            if (c4 == 0) {
                float Dv = (dp == 0.f) ? EPS_C : dp;
                dinv[row] = 1.f / Dv;
            }
            v1t[c4 * 4 + 0][row] = v1.x;
            v1t[c4 * 4 + 1][row] = v1.y;
            v1t[c4 * 4 + 2][row] = v1.z;
            v1t[c4 * 4 + 3][row] = v1.w;
        }
        __syncthreads();
        // ---- X_tile = v1 @ context ----
        float acc[4][4];
#pragma unroll
        for (int i = 0; i < 4; ++i)
#pragma unroll
            for (int j = 0; j < 4; ++j) acc[i][j] = 0.f;
#pragma unroll 4
        for (int d = 0; d < DH; ++d) {
            float4 a = *(const float4*)&v1t[d][ty * 4];    // 4 tokens at dim d
            float4 b = *(const float4*)&ctxs[d][tx * 4];   // 4 output dims
            float av[4] = {a.x, a.y, a.z, a.w};
            float bv[4] = {b.x, b.y, b.z, b.w};
#pragma unroll
            for (int i = 0; i < 4; ++i)
#pragma unroll
                for (int j = 0; j < 4; ++j)
                    acc[i][j] = fmaf(av[i], bv[j], acc[i][j]);
        }
        // ---- epilogue: Dinv scale, project -> mobius(0.5) -> project ----
#pragma unroll
        for (int i = 0; i < 4; ++i) {
            int row  = ty * 4 + i;
            float dv = dinv[row];
            float x0 = acc[i][0] * dv;
            float x1 = acc[i][1] * dv;
            float x2 = acc[i][2] * dv;
            float x3 = acc[i][3] * dv;
            float n2 = x0 * x0 + x1 * x1 + x2 * x2 + x3 * x3;
            n2 += __shfl_xor(n2, 1);
            n2 += __shfl_xor(n2, 2);
            n2 += __shfl_xor(n2, 4);
            n2 += __shfl_xor(n2, 8);
            float n  = fmaxf(sqrtf(n2), MIN_NORM_C);
            float scale = 1.f;
            float n1 = n;
            if (n > maxnorm) { scale = maxnorm / n; n1 = maxnorm; }
            float xn = fmaxf(n1, MIN_NORM_C);
            float tval;
            if (k < 0.f) {
                float inner = fminf(sk * xn, 1.f - 1e-7f);
                float ar = atanhf(inner) / sk;          // artan_k
                tval = tanhf(sk * (0.5f * ar)) / sk;    // tan_k(0.5 * artan)
            } else {
                float ar = atanf(sk * xn) / sk;
                tval = tanf(sk * (0.5f * ar)) / sk;
            }
            float s2 = tval / xn;
            scale *= s2;
            float nrm2 = fmaxf(n1 * s2, MIN_NORM_C);
            if (nrm2 > maxnorm) scale *= maxnorm / nrm2;
            float4 o;
            o.x = x0 * scale; o.y = x1 * scale;
            o.z = x2 * scale; o.w = x3 * scale;
            int gtok = tbase + tt + row;
            *(float4*)(outp + (size_t)gtok * DH + tx * 4) = o;
        }
        __syncthreads();   // protect v1t/dinv before next tile
    }
}

extern "C" void kernel_launch(void* const* d_in, const int* in_sizes, int n_in,
                              void* d_out, int out_size, void* d_ws, size_t ws_size,
                              hipStream_t stream)
{
    const float* Q    = (const float*)d_in[0];
    const float* K    = (const float*)d_in[1];
    const float* V    = (const float*)d_in[2];
    const float* mask = (const float*)d_in[3];
    const float* c    = (const float*)d_in[4];
    const int csize   = in_sizes[4];
    const int BH      = in_sizes[0] / (NTOK * DH);   // 64
    const int H       = 16;
    float* out        = (float*)d_out;

    // workspace layout: pt[BH*NTOK] | v2sum[BH*64] | ctx[BH*64*64]
    float* pt    = (float*)d_ws;
    float* v2sum = pt + (size_t)BH * NTOK;
    float* ctx   = v2sum + (size_t)BH * DH;

    // zero the atomic accumulation region (ws is poisoned to 0xAA each launch)
    hipMemsetAsync(v2sum, 0,
                   ((size_t)BH * DH + (size_t)BH * DH * DH) * sizeof(float),
                   stream);

    dim3 grid(BH, NCHUNK);
    glin_phase1<<<grid, 256, 0, stream>>>(K, V, mask, c, csize, H, pt, v2sum, ctx);
    glin_phase2<<<grid, 256, 0, stream>>>(Q, c, csize, H, pt, v2sum, ctx, out);
}